// Round 1
// baseline (354.437 us; speedup 1.0000x reference)
//
#include <hip/hip_runtime.h>
#include <stdint.h>

typedef short short8 __attribute__((ext_vector_type(8)));
typedef float f32x4 __attribute__((ext_vector_type(4)));
typedef unsigned int u32;
typedef unsigned short u16;

#define HH 512
#define WW 512
#define CC 64
#define TH 4
#define TW 64
#define SR 6
#define SC 68
#define PLANE (HH*WW)
#define NBLK 2048
#define NSTATF 524288.0f

__device__ __forceinline__ u16 f2bf(float f) {
  u32 x = __builtin_bit_cast(u32, f);
  x += 0x7FFFu + ((x >> 16) & 1u);
  return (u16)(x >> 16);
}
__device__ __forceinline__ float bf2f(u16 u) {
  u32 x = ((u32)u) << 16;
  return __builtin_bit_cast(float, x);
}

// ---------------- K1: conv1 (3x3) + projection (1x1), bf16 MFMA ----------------
// y1: NHWC bf16 (for vectorized restaging in K3); yp: NCHW bf16.
// BN partial sums (per channel, per block) written deterministically.
__global__ __launch_bounds__(256) void k1(const float* __restrict__ x,
    const float* __restrict__ w1, const float* __restrict__ b1,
    const float* __restrict__ wp, const float* __restrict__ bp,
    u16* __restrict__ y1, u16* __restrict__ yp,
    float* __restrict__ ps1, float* __restrict__ pq1,
    float* __restrict__ psp, float* __restrict__ pqp)
{
  __shared__ __align__(16) char L[SR*SC*CC*2];
  const int tid = threadIdx.x;
  const int lane = tid & 63, wv = tid >> 6;
  const int l15 = lane & 15, qq = lane >> 4;
  const int wt = blockIdx.x, ht = blockIdx.y, nb = blockIdx.z;
  const int w0 = wt*TW, h0 = ht*TH;
  const int bid = (nb*128 + ht)*8 + wt;
  const int coutA = wv*16 + l15;

  // weight fragments: w1 as A-operand (row = cout, k = cin)
  short8 wf[9][2];
#pragma unroll
  for (int tap = 0; tap < 9; ++tap) {
#pragma unroll
    for (int kb = 0; kb < 2; ++kb) {
      short8 v;
#pragma unroll
      for (int r = 0; r < 8; ++r) {
        int ci = kb*32 + qq*8 + r;
        v[r] = (short)f2bf(w1[(coutA*CC + ci)*9 + tap]);
      }
      wf[tap][kb] = v;
    }
  }
  // wp as B-operand (col = cout, k = cin)
  short8 wpf[2];
#pragma unroll
  for (int kb = 0; kb < 2; ++kb) {
    short8 v;
#pragma unroll
    for (int r = 0; r < 8; ++r) v[r] = (short)f2bf(wp[coutA*CC + kb*32 + qq*8 + r]);
    wpf[kb] = v;
  }
  float b1v[4];
#pragma unroll
  for (int r = 0; r < 4; ++r) b1v[r] = b1[wv*16 + qq*4 + r];
  const float bpv = bp[coutA];

  // ---- stage x tile to LDS (bf16, channel-minor, XOR-swizzled) ----
  const float* xn = x + (size_t)nb*CC*PLANE;
  for (int idx = tid; idx < SR*SC; idx += 256) {
    const int row = idx / SC, col = idx - row*SC;
    const int gh = h0 - 1 + row, gw = w0 - 1 + col;
    const bool ok = (gh >= 0) && (gh < HH) && (gw >= 0) && (gw < WW);
    const float* p = xn + (ok ? ((size_t)gh*WW + gw) : 0);
    const u32 lb = (u32)(row*SC + col)*128u;
    const u32 sw = (u32)(col & 7) << 4;
#pragma unroll
    for (int c4 = 0; c4 < 16; ++c4) {
      float v0 = ok ? p[(c4*4+0)*PLANE] : 0.f;
      float v1 = ok ? p[(c4*4+1)*PLANE] : 0.f;
      float v2 = ok ? p[(c4*4+2)*PLANE] : 0.f;
      float v3 = ok ? p[(c4*4+3)*PLANE] : 0.f;
      uint2 pk;
      pk.x = (u32)f2bf(v0) | ((u32)f2bf(v1) << 16);
      pk.y = (u32)f2bf(v2) | ((u32)f2bf(v3) << 16);
      *(uint2*)(L + ((lb + (u32)(c4*8)) ^ sw)) = pk;
    }
  }
  __syncthreads();

  // per-lane swizzled LDS read bases
  u32 pre[2][3];
#pragma unroll
  for (int kb = 0; kb < 2; ++kb)
#pragma unroll
    for (int kw = 0; kw < 3; ++kw)
      pre[kb][kw] = ((u32)(l15*128 + kb*64 + qq*16)) ^ ((u32)((kw + l15) & 7) << 4);

  float s1[4] = {0,0,0,0}, sq1[4] = {0,0,0,0};
  float sp = 0.f, sqp = 0.f;

  for (int m = 0; m < 16; ++m) {
    const int rm = m >> 2, cb = (m & 3) << 4;
    f32x4 acc = {0.f, 0.f, 0.f, 0.f};
    short8 c0, c1;
#pragma unroll
    for (int kh = 0; kh < 3; ++kh) {
      const u32 rb = (u32)(((rm + kh)*SC + cb)*128);
#pragma unroll
      for (int kw = 0; kw < 3; ++kw) {
        const short8 x0 = *(const short8*)(L + (rb + (u32)(kw*128) + pre[0][kw]));
        const short8 x1 = *(const short8*)(L + (rb + (u32)(kw*128) + pre[1][kw]));
        acc = __builtin_amdgcn_mfma_f32_16x16x32_bf16(wf[kh*3+kw][0], x0, acc, 0, 0, 0);
        acc = __builtin_amdgcn_mfma_f32_16x16x32_bf16(wf[kh*3+kw][1], x1, acc, 0, 0, 0);
        if (kh == 1 && kw == 1) { c0 = x0; c1 = x1; }
      }
    }
    const int ghh = h0 + rm;
#pragma unroll
    for (int r = 0; r < 4; ++r) {
      float a = acc[r] + b1v[r];
      acc[r] = a;
      s1[r] += a; sq1[r] += a*a;
    }
    { // y1 NHWC: lane holds 4 consecutive couts at one spatial position
      const int gw = w0 + cb + l15;
      u16* dst = y1 + ((size_t)((nb*HH + ghh)*WW + gw))*CC + (wv*16 + qq*4);
      uint2 pk;
      pk.x = (u32)f2bf(acc[0]) | ((u32)f2bf(acc[1]) << 16);
      pk.y = (u32)f2bf(acc[2]) | ((u32)f2bf(acc[3]) << 16);
      *(uint2*)dst = pk;
    }
    // projection: x-as-A, wp-as-B -> lane holds 4 consecutive w at one cout
    f32x4 pacc = {0.f,0.f,0.f,0.f};
    pacc = __builtin_amdgcn_mfma_f32_16x16x32_bf16(c0, wpf[0], pacc, 0, 0, 0);
    pacc = __builtin_amdgcn_mfma_f32_16x16x32_bf16(c1, wpf[1], pacc, 0, 0, 0);
#pragma unroll
    for (int r = 0; r < 4; ++r) {
      float a = pacc[r] + bpv;
      pacc[r] = a;
      sp += a; sqp += a*a;
    }
    {
      const int gw = w0 + cb + qq*4;
      u16* dst = yp + ((size_t)((nb*CC + coutA)*HH + ghh))*WW + gw;
      uint2 pk;
      pk.x = (u32)f2bf(pacc[0]) | ((u32)f2bf(pacc[1]) << 16);
      pk.y = (u32)f2bf(pacc[2]) | ((u32)f2bf(pacc[3]) << 16);
      *(uint2*)dst = pk;
    }
  }

  // conv1 stats: reduce across spatial (l15 bits)
#pragma unroll
  for (int d = 1; d <= 8; d <<= 1) {
#pragma unroll
    for (int r = 0; r < 4; ++r) {
      s1[r] += __shfl_xor(s1[r], d, 64);
      sq1[r] += __shfl_xor(sq1[r], d, 64);
    }
  }
  if (l15 == 0) {
#pragma unroll
    for (int r = 0; r < 4; ++r) {
      const int c = wv*16 + qq*4 + r;
      ps1[(size_t)c*NBLK + bid] = s1[r];
      pq1[(size_t)c*NBLK + bid] = sq1[r];
    }
  }
  // proj stats: reduce across spatial (q bits)
  sp += __shfl_xor(sp, 16, 64); sp += __shfl_xor(sp, 32, 64);
  sqp += __shfl_xor(sqp, 16, 64); sqp += __shfl_xor(sqp, 32, 64);
  if (qq == 0) {
    psp[(size_t)coutA*NBLK + bid] = sp;
    pqp[(size_t)coutA*NBLK + bid] = sqp;
  }
}

// ---------------- finalize BN stats: mean/var -> scale A, shift Bc ----------------
__global__ __launch_bounds__(256) void kfin(const float* __restrict__ ps, const float* __restrict__ pq,
    const float* __restrict__ g, const float* __restrict__ be,
    float* __restrict__ A, float* __restrict__ Bc)
{
  const int c = blockIdx.x, t = threadIdx.x;
  float s = 0.f, s2 = 0.f;
  const float* pr = ps + (size_t)c*NBLK;
  const float* qr = pq + (size_t)c*NBLK;
  for (int k = t; k < NBLK; k += 256) { s += pr[k]; s2 += qr[k]; }
#pragma unroll
  for (int d = 1; d < 64; d <<= 1) { s += __shfl_xor(s, d, 64); s2 += __shfl_xor(s2, d, 64); }
  __shared__ float as_[4], aq_[4];
  if ((t & 63) == 0) { as_[t >> 6] = s; aq_[t >> 6] = s2; }
  __syncthreads();
  if (t == 0) {
    s  = as_[0] + as_[1] + as_[2] + as_[3];
    s2 = aq_[0] + aq_[1] + aq_[2] + aq_[3];
    const float mean = s / NSTATF;
    const float var = s2 / NSTATF - mean*mean;
    const float istd = rsqrtf(var + 1e-5f);
    const float a = g[c] * istd;
    A[c] = a;
    Bc[c] = be[c] - mean * a;
  }
}

// ---------------- K3: conv2 (3x3) with fused BN1+ReLU on staging ----------------
__global__ __launch_bounds__(256) void k3(const u16* __restrict__ y1,
    const float* __restrict__ w2, const float* __restrict__ b2,
    const float* __restrict__ A1, const float* __restrict__ B1,
    u16* __restrict__ y2, float* __restrict__ ps2, float* __restrict__ pq2)
{
  __shared__ __align__(16) char L[SR*SC*CC*2];
  __shared__ float sA[CC], sB[CC];
  const int tid = threadIdx.x;
  const int lane = tid & 63, wv = tid >> 6;
  const int l15 = lane & 15, qq = lane >> 4;
  const int wt = blockIdx.x, ht = blockIdx.y, nb = blockIdx.z;
  const int w0 = wt*TW, h0 = ht*TH;
  const int bid = (nb*128 + ht)*8 + wt;
  const int coutA = wv*16 + l15;

  if (tid < CC) { sA[tid] = A1[tid]; sB[tid] = B1[tid]; }

  // w2 as B-operand (col = cout, k = cin)
  short8 wf[9][2];
#pragma unroll
  for (int tap = 0; tap < 9; ++tap) {
#pragma unroll
    for (int kb = 0; kb < 2; ++kb) {
      short8 v;
#pragma unroll
      for (int r = 0; r < 8; ++r) {
        int ci = kb*32 + qq*8 + r;
        v[r] = (short)f2bf(w2[(coutA*CC + ci)*9 + tap]);
      }
      wf[tap][kb] = v;
    }
  }
  const float b2v = b2[coutA];
  __syncthreads();

  // stage relu(bn1(y1)) tile; y1 is NHWC bf16 so 16B chunks are 8 channels
  const u16* yn = y1 + (size_t)nb*PLANE*CC;
  for (int idx = tid; idx < SR*SC; idx += 256) {
    const int row = idx / SC, col = idx - row*SC;
    const int gh = h0 - 1 + row, gw = w0 - 1 + col;
    const bool ok = (gh >= 0) && (gh < HH) && (gw >= 0) && (gw < WW);
    const u16* p = yn + (ok ? ((size_t)gh*WW + gw)*CC : 0);
    const u32 lb = (u32)(row*SC + col)*128u;
    const u32 sw = (u32)(col & 7) << 4;
#pragma unroll
    for (int c8 = 0; c8 < 8; ++c8) {
      uint4 pk = make_uint4(0u,0u,0u,0u);
      if (ok) {
        const uint4 u = *(const uint4*)(p + c8*8);
        const u32* uw = (const u32*)&u;
        u32 ow[4];
#pragma unroll
        for (int h2 = 0; h2 < 4; ++h2) {
          const int cidx = c8*8 + h2*2;
          float f0 = bf2f((u16)(uw[h2] & 0xFFFFu));
          float f1 = bf2f((u16)(uw[h2] >> 16));
          f0 = fmaxf(f0*sA[cidx]   + sB[cidx],   0.f);
          f1 = fmaxf(f1*sA[cidx+1] + sB[cidx+1], 0.f);
          ow[h2] = (u32)f2bf(f0) | ((u32)f2bf(f1) << 16);
        }
        pk = make_uint4(ow[0], ow[1], ow[2], ow[3]);
      }
      *(uint4*)(L + ((lb + (u32)(c8*16)) ^ sw)) = pk;
    }
  }
  __syncthreads();

  u32 pre[2][3];
#pragma unroll
  for (int kb = 0; kb < 2; ++kb)
#pragma unroll
    for (int kw = 0; kw < 3; ++kw)
      pre[kb][kw] = ((u32)(l15*128 + kb*64 + qq*16)) ^ ((u32)((kw + l15) & 7) << 4);

  float ss = 0.f, sqs = 0.f;
  for (int m = 0; m < 16; ++m) {
    const int rm = m >> 2, cb = (m & 3) << 4;
    f32x4 acc = {0.f,0.f,0.f,0.f};
#pragma unroll
    for (int kh = 0; kh < 3; ++kh) {
      const u32 rb = (u32)(((rm + kh)*SC + cb)*128);
#pragma unroll
      for (int kw = 0; kw < 3; ++kw) {
        const short8 x0 = *(const short8*)(L + (rb + (u32)(kw*128) + pre[0][kw]));
        const short8 x1 = *(const short8*)(L + (rb + (u32)(kw*128) + pre[1][kw]));
        acc = __builtin_amdgcn_mfma_f32_16x16x32_bf16(x0, wf[kh*3+kw][0], acc, 0, 0, 0);
        acc = __builtin_amdgcn_mfma_f32_16x16x32_bf16(x1, wf[kh*3+kw][1], acc, 0, 0, 0);
      }
    }
#pragma unroll
    for (int r = 0; r < 4; ++r) {
      float a = acc[r] + b2v;
      acc[r] = a;
      ss += a; sqs += a*a;
    }
    {
      const int gw = w0 + cb + qq*4;
      u16* dst = y2 + ((size_t)((nb*CC + coutA)*HH + (h0 + rm)))*WW + gw;
      uint2 pk;
      pk.x = (u32)f2bf(acc[0]) | ((u32)f2bf(acc[1]) << 16);
      pk.y = (u32)f2bf(acc[2]) | ((u32)f2bf(acc[3]) << 16);
      *(uint2*)dst = pk;
    }
  }
  ss  += __shfl_xor(ss, 16, 64);  ss  += __shfl_xor(ss, 32, 64);
  sqs += __shfl_xor(sqs, 16, 64); sqs += __shfl_xor(sqs, 32, 64);
  if (qq == 0) {
    ps2[(size_t)coutA*NBLK + bid] = ss;
    pq2[(size_t)coutA*NBLK + bid] = sqs;
  }
}

// ---------------- K5: out = relu(bn2(y2) + bnp(yp)), NCHW fp32 ----------------
__global__ __launch_bounds__(256) void k5(const u16* __restrict__ y2, const u16* __restrict__ yp,
    const float* __restrict__ A2, const float* __restrict__ B2,
    const float* __restrict__ Ap, const float* __restrict__ Bp,
    float* __restrict__ out)
{
  const size_t base = ((size_t)blockIdx.x*256 + threadIdx.x)*8;
  const int c = (int)((base >> 18) & 63);
  const float a2 = A2[c], b2 = B2[c], ap = Ap[c], bp = Bp[c];
  const uint4 u2 = *(const uint4*)(y2 + base);
  const uint4 up = *(const uint4*)(yp + base);
  const u32* m2 = (const u32*)&u2;
  const u32* mp = (const u32*)&up;
  float ov[8];
#pragma unroll
  for (int h2 = 0; h2 < 4; ++h2) {
    float a = bf2f((u16)(m2[h2] & 0xFFFFu));
    float b = bf2f((u16)(m2[h2] >> 16));
    float ra = bf2f((u16)(mp[h2] & 0xFFFFu));
    float rb = bf2f((u16)(mp[h2] >> 16));
    ov[h2*2]   = fmaxf(a*a2 + b2 + ra*ap + bp, 0.f);
    ov[h2*2+1] = fmaxf(b*a2 + b2 + rb*ap + bp, 0.f);
  }
  f32x4* o = (f32x4*)(out + base);
  o[0] = (f32x4){ov[0],ov[1],ov[2],ov[3]};
  o[1] = (f32x4){ov[4],ov[5],ov[6],ov[7]};
}

extern "C" void kernel_launch(void* const* d_in, const int* in_sizes, int n_in,
                              void* d_out, int out_size, void* d_ws, size_t ws_size,
                              hipStream_t stream)
{
  (void)in_sizes; (void)n_in; (void)out_size;
  const float* x   = (const float*)d_in[0];
  const float* w1  = (const float*)d_in[1];
  const float* b1  = (const float*)d_in[2];
  const float* g1  = (const float*)d_in[3];
  const float* be1 = (const float*)d_in[4];
  const float* w2  = (const float*)d_in[5];
  const float* b2  = (const float*)d_in[6];
  const float* g2  = (const float*)d_in[7];
  const float* be2 = (const float*)d_in[8];
  const float* wp  = (const float*)d_in[9];
  const float* bp  = (const float*)d_in[10];
  const float* gp  = (const float*)d_in[11];
  const float* bep = (const float*)d_in[12];

  const size_t TEN = (size_t)2*CC*PLANE;          // 33,554,432 elements
  const size_t need = TEN*2*3 + (size_t)6*CC*NBLK*4 + 6*CC*4;
  if (ws_size < need) return;  // workspace too small: fail loudly (wrong output)

  char* ws = (char*)d_ws;
  u16* y1 = (u16*)ws;                 // NHWC bf16
  u16* yp = (u16*)(ws + TEN*2);       // NCHW bf16
  u16* y2 = (u16*)(ws + TEN*4);       // NCHW bf16
  float* ps1 = (float*)(ws + TEN*6);
  float* pq1 = ps1 + (size_t)CC*NBLK;
  float* psp = pq1 + (size_t)CC*NBLK;
  float* pqp = psp + (size_t)CC*NBLK;
  float* ps2 = pqp + (size_t)CC*NBLK;
  float* pq2 = ps2 + (size_t)CC*NBLK;
  float* A1  = pq2 + (size_t)CC*NBLK;
  float* B1  = A1 + CC;
  float* Ap  = B1 + CC;
  float* Bp  = Ap + CC;
  float* A2  = Bp + CC;
  float* B2c = A2 + CC;

  dim3 grid(WW/TW, HH/TH, 2);
  k1<<<grid, 256, 0, stream>>>(x, w1, b1, wp, bp, y1, yp, ps1, pq1, psp, pqp);
  kfin<<<CC, 256, 0, stream>>>(ps1, pq1, g1, be1, A1, B1);
  kfin<<<CC, 256, 0, stream>>>(psp, pqp, gp, bep, Ap, Bp);
  k3<<<grid, 256, 0, stream>>>(y1, w2, b2, A1, B1, y2, ps2, pq2);
  kfin<<<CC, 256, 0, stream>>>(ps2, pq2, g2, be2, A2, B2c);
  k5<<<(int)(TEN/(256*8)), 256, 0, stream>>>(y2, yp, A2, B2c, Ap, Bp, (float*)d_out);
}

// Round 2
// 310.858 us; speedup vs baseline: 1.1402x; 1.1402x over previous
//
#include <hip/hip_runtime.h>
#include <stdint.h>

typedef short short8 __attribute__((ext_vector_type(8)));
typedef float f32x4 __attribute__((ext_vector_type(4)));
typedef unsigned int u32;
typedef unsigned short u16;

#define HH 512
#define WW 512
#define CC 64
#define TH 4
#define TW 64
#define SR 6
#define SC 68
#define PLANE (HH*WW)
#define NBLK 2048
#define NSTATF 524288.0f
#define TS 258  // u16 row stride in k0 transpose tile (odd dword stride -> conflict-free)

__device__ __forceinline__ u16 f2bf(float f) {
  u32 x = __builtin_bit_cast(u32, f);
  x += 0x7FFFu + ((x >> 16) & 1u);
  return (u16)(x >> 16);
}
__device__ __forceinline__ float bf2f(u16 u) {
  u32 x = ((u32)u) << 16;
  return __builtin_bit_cast(float, x);
}

// ---------------- K0: x NCHW fp32 -> xh NHWC bf16 (coalesced transpose) ----------------
__global__ __launch_bounds__(256) void k0(const float* __restrict__ x, u16* __restrict__ xh)
{
  __shared__ u16 T[CC * TS];
  const int tid = threadIdx.x;
  const int wt = blockIdx.x, h = blockIdx.y, n = blockIdx.z;
  const int w0 = wt * 256;
  const float* xp = x + (size_t)n*CC*PLANE + (size_t)h*WW + w0;
  // read: per (c) 1KB contiguous; convert; store into [c][w] tile
#pragma unroll
  for (int it = 0; it < 16; ++it) {
    const int j = it*256 + tid;
    const int c = j >> 6, w4 = (j & 63) << 2;
    const f32x4 v = *(const f32x4*)(xp + (size_t)c*PLANE + w4);
    const u32 lo = (u32)f2bf(v[0]) | ((u32)f2bf(v[1]) << 16);
    const u32 hi = (u32)f2bf(v[2]) | ((u32)f2bf(v[3]) << 16);
    u16* tp = T + c*TS + w4;
    *(u32*)(tp)     = lo;
    *(u32*)(tp + 2) = hi;
  }
  __syncthreads();
  // write: gather 8 channels per thread -> uint4, NHWC contiguous
  u16* op = xh + ((size_t)(n*HH + h)*WW + w0)*CC;
#pragma unroll
  for (int it = 0; it < 8; ++it) {
    const int j = it*256 + tid;
    const int w = j >> 3, c8 = j & 7;
    u32 ow[4];
#pragma unroll
    for (int p2 = 0; p2 < 4; ++p2) {
      const u32 lo = T[(c8*8 + p2*2    )*TS + w];
      const u32 hi = T[(c8*8 + p2*2 + 1)*TS + w];
      ow[p2] = lo | (hi << 16);
    }
    *(uint4*)(op + (size_t)w*CC + c8*8) = make_uint4(ow[0], ow[1], ow[2], ow[3]);
  }
}

// ---------------- K1: conv1 (3x3) + projection (1x1), bf16 MFMA ----------------
// stages from xh (NHWC bf16) with pure uint4 copies; y1: NHWC bf16; yp: NCHW bf16.
__global__ __launch_bounds__(256) void k1(const u16* __restrict__ xh,
    const float* __restrict__ w1, const float* __restrict__ b1,
    const float* __restrict__ wp, const float* __restrict__ bp,
    u16* __restrict__ y1, u16* __restrict__ yp,
    float* __restrict__ ps1, float* __restrict__ pq1,
    float* __restrict__ psp, float* __restrict__ pqp)
{
  __shared__ __align__(16) char L[SR*SC*CC*2];
  const int tid = threadIdx.x;
  const int lane = tid & 63, wv = tid >> 6;
  const int l15 = lane & 15, qq = lane >> 4;
  const int wt = blockIdx.x, ht = blockIdx.y, nb = blockIdx.z;
  const int w0 = wt*TW, h0 = ht*TH;
  const int bid = (nb*128 + ht)*8 + wt;
  const int coutA = wv*16 + l15;

  // weight fragments: w1 as A-operand (row = cout, k = cin)
  short8 wf[9][2];
#pragma unroll
  for (int tap = 0; tap < 9; ++tap) {
#pragma unroll
    for (int kb = 0; kb < 2; ++kb) {
      short8 v;
#pragma unroll
      for (int r = 0; r < 8; ++r) {
        int ci = kb*32 + qq*8 + r;
        v[r] = (short)f2bf(w1[(coutA*CC + ci)*9 + tap]);
      }
      wf[tap][kb] = v;
    }
  }
  // wp as B-operand (col = cout, k = cin)
  short8 wpf[2];
#pragma unroll
  for (int kb = 0; kb < 2; ++kb) {
    short8 v;
#pragma unroll
    for (int r = 0; r < 8; ++r) v[r] = (short)f2bf(wp[coutA*CC + kb*32 + qq*8 + r]);
    wpf[kb] = v;
  }
  float b1v[4];
#pragma unroll
  for (int r = 0; r < 4; ++r) b1v[r] = b1[wv*16 + qq*4 + r];
  const float bpv = bp[coutA];

  // ---- stage xh tile to LDS (bf16 NHWC, XOR-swizzled) ----
  const u16* xn = xh + (size_t)nb*PLANE*CC;
  for (int idx = tid; idx < SR*SC; idx += 256) {
    const int row = idx / SC, col = idx - row*SC;
    const int gh = h0 - 1 + row, gw = w0 - 1 + col;
    const bool ok = (gh >= 0) && (gh < HH) && (gw >= 0) && (gw < WW);
    const u16* p = xn + (ok ? ((size_t)gh*WW + gw)*CC : 0);
    const u32 lb = (u32)(row*SC + col)*128u;
    const u32 sw = (u32)(col & 7) << 4;
#pragma unroll
    for (int c8 = 0; c8 < 8; ++c8) {
      uint4 pk = make_uint4(0u,0u,0u,0u);
      if (ok) pk = *(const uint4*)(p + c8*8);
      *(uint4*)(L + ((lb + (u32)(c8*16)) ^ sw)) = pk;
    }
  }
  __syncthreads();

  // per-lane swizzled LDS read bases
  u32 pre[2][3];
#pragma unroll
  for (int kb = 0; kb < 2; ++kb)
#pragma unroll
    for (int kw = 0; kw < 3; ++kw)
      pre[kb][kw] = ((u32)(l15*128 + kb*64 + qq*16)) ^ ((u32)((kw + l15) & 7) << 4);

  float s1[4] = {0,0,0,0}, sq1[4] = {0,0,0,0};
  float sp = 0.f, sqp = 0.f;

  for (int m = 0; m < 16; ++m) {
    const int rm = m >> 2, cb = (m & 3) << 4;
    f32x4 acc = {0.f, 0.f, 0.f, 0.f};
    short8 c0, c1;
#pragma unroll
    for (int kh = 0; kh < 3; ++kh) {
      const u32 rb = (u32)(((rm + kh)*SC + cb)*128);
#pragma unroll
      for (int kw = 0; kw < 3; ++kw) {
        const short8 x0 = *(const short8*)(L + (rb + (u32)(kw*128) + pre[0][kw]));
        const short8 x1 = *(const short8*)(L + (rb + (u32)(kw*128) + pre[1][kw]));
        acc = __builtin_amdgcn_mfma_f32_16x16x32_bf16(wf[kh*3+kw][0], x0, acc, 0, 0, 0);
        acc = __builtin_amdgcn_mfma_f32_16x16x32_bf16(wf[kh*3+kw][1], x1, acc, 0, 0, 0);
        if (kh == 1 && kw == 1) { c0 = x0; c1 = x1; }
      }
    }
    const int ghh = h0 + rm;
#pragma unroll
    for (int r = 0; r < 4; ++r) {
      float a = acc[r] + b1v[r];
      acc[r] = a;
      s1[r] += a; sq1[r] += a*a;
    }
    { // y1 NHWC: lane holds 4 consecutive couts at one spatial position
      const int gw = w0 + cb + l15;
      u16* dst = y1 + ((size_t)((nb*HH + ghh)*WW + gw))*CC + (wv*16 + qq*4);
      uint2 pk;
      pk.x = (u32)f2bf(acc[0]) | ((u32)f2bf(acc[1]) << 16);
      pk.y = (u32)f2bf(acc[2]) | ((u32)f2bf(acc[3]) << 16);
      *(uint2*)dst = pk;
    }
    // projection: x-as-A, wp-as-B -> lane holds 4 consecutive w at one cout
    f32x4 pacc = {0.f,0.f,0.f,0.f};
    pacc = __builtin_amdgcn_mfma_f32_16x16x32_bf16(c0, wpf[0], pacc, 0, 0, 0);
    pacc = __builtin_amdgcn_mfma_f32_16x16x32_bf16(c1, wpf[1], pacc, 0, 0, 0);
#pragma unroll
    for (int r = 0; r < 4; ++r) {
      float a = pacc[r] + bpv;
      pacc[r] = a;
      sp += a; sqp += a*a;
    }
    {
      const int gw = w0 + cb + qq*4;
      u16* dst = yp + ((size_t)((nb*CC + coutA)*HH + ghh))*WW + gw;
      uint2 pk;
      pk.x = (u32)f2bf(pacc[0]) | ((u32)f2bf(pacc[1]) << 16);
      pk.y = (u32)f2bf(pacc[2]) | ((u32)f2bf(pacc[3]) << 16);
      *(uint2*)dst = pk;
    }
  }

  // conv1 stats: reduce across spatial (l15 bits)
#pragma unroll
  for (int d = 1; d <= 8; d <<= 1) {
#pragma unroll
    for (int r = 0; r < 4; ++r) {
      s1[r] += __shfl_xor(s1[r], d, 64);
      sq1[r] += __shfl_xor(sq1[r], d, 64);
    }
  }
  if (l15 == 0) {
#pragma unroll
    for (int r = 0; r < 4; ++r) {
      const int c = wv*16 + qq*4 + r;
      ps1[(size_t)c*NBLK + bid] = s1[r];
      pq1[(size_t)c*NBLK + bid] = sq1[r];
    }
  }
  // proj stats: reduce across spatial (q bits)
  sp += __shfl_xor(sp, 16, 64); sp += __shfl_xor(sp, 32, 64);
  sqp += __shfl_xor(sqp, 16, 64); sqp += __shfl_xor(sqp, 32, 64);
  if (qq == 0) {
    psp[(size_t)coutA*NBLK + bid] = sp;
    pqp[(size_t)coutA*NBLK + bid] = sqp;
  }
}

// ---------------- finalize BN stats (two sets in one launch) ----------------
__global__ __launch_bounds__(256) void kfin2(
    const float* __restrict__ psA, const float* __restrict__ pqA,
    const float* __restrict__ gA, const float* __restrict__ beA,
    float* __restrict__ AA, float* __restrict__ BA,
    const float* __restrict__ psB, const float* __restrict__ pqB,
    const float* __restrict__ gB, const float* __restrict__ beB,
    float* __restrict__ AB, float* __restrict__ BB)
{
  const int blk = blockIdx.x;
  const int c = blk & (CC - 1);
  const bool second = blk >= CC;
  const float* ps = second ? psB : psA;
  const float* pq = second ? pqB : pqA;
  const float* g  = second ? gB  : gA;
  const float* be = second ? beB : beA;
  float* A  = second ? AB : AA;
  float* Bc = second ? BB : BA;

  const int t = threadIdx.x;
  float s = 0.f, s2 = 0.f;
  const float* pr = ps + (size_t)c*NBLK;
  const float* qr = pq + (size_t)c*NBLK;
  for (int k = t; k < NBLK; k += 256) { s += pr[k]; s2 += qr[k]; }
#pragma unroll
  for (int d = 1; d < 64; d <<= 1) { s += __shfl_xor(s, d, 64); s2 += __shfl_xor(s2, d, 64); }
  __shared__ float as_[4], aq_[4];
  if ((t & 63) == 0) { as_[t >> 6] = s; aq_[t >> 6] = s2; }
  __syncthreads();
  if (t == 0) {
    s  = as_[0] + as_[1] + as_[2] + as_[3];
    s2 = aq_[0] + aq_[1] + aq_[2] + aq_[3];
    const float mean = s / NSTATF;
    const float var = s2 / NSTATF - mean*mean;
    const float istd = rsqrtf(var + 1e-5f);
    const float a = g[c] * istd;
    A[c] = a;
    Bc[c] = be[c] - mean * a;
  }
}

// ---------------- K3: conv2 (3x3) with fused BN1+ReLU on staging ----------------
__global__ __launch_bounds__(256) void k3(const u16* __restrict__ y1,
    const float* __restrict__ w2, const float* __restrict__ b2,
    const float* __restrict__ A1, const float* __restrict__ B1,
    u16* __restrict__ y2, float* __restrict__ ps2, float* __restrict__ pq2)
{
  __shared__ __align__(16) char L[SR*SC*CC*2];
  __shared__ float sA[CC], sB[CC];
  const int tid = threadIdx.x;
  const int lane = tid & 63, wv = tid >> 6;
  const int l15 = lane & 15, qq = lane >> 4;
  const int wt = blockIdx.x, ht = blockIdx.y, nb = blockIdx.z;
  const int w0 = wt*TW, h0 = ht*TH;
  const int bid = (nb*128 + ht)*8 + wt;
  const int coutA = wv*16 + l15;

  if (tid < CC) { sA[tid] = A1[tid]; sB[tid] = B1[tid]; }

  // w2 as B-operand (col = cout, k = cin)
  short8 wf[9][2];
#pragma unroll
  for (int tap = 0; tap < 9; ++tap) {
#pragma unroll
    for (int kb = 0; kb < 2; ++kb) {
      short8 v;
#pragma unroll
      for (int r = 0; r < 8; ++r) {
        int ci = kb*32 + qq*8 + r;
        v[r] = (short)f2bf(w2[(coutA*CC + ci)*9 + tap]);
      }
      wf[tap][kb] = v;
    }
  }
  const float b2v = b2[coutA];
  __syncthreads();

  // stage relu(bn1(y1)) tile; y1 is NHWC bf16 so 16B chunks are 8 channels
  const u16* yn = y1 + (size_t)nb*PLANE*CC;
  for (int idx = tid; idx < SR*SC; idx += 256) {
    const int row = idx / SC, col = idx - row*SC;
    const int gh = h0 - 1 + row, gw = w0 - 1 + col;
    const bool ok = (gh >= 0) && (gh < HH) && (gw >= 0) && (gw < WW);
    const u16* p = yn + (ok ? ((size_t)gh*WW + gw)*CC : 0);
    const u32 lb = (u32)(row*SC + col)*128u;
    const u32 sw = (u32)(col & 7) << 4;
#pragma unroll
    for (int c8 = 0; c8 < 8; ++c8) {
      uint4 pk = make_uint4(0u,0u,0u,0u);
      if (ok) {
        const uint4 u = *(const uint4*)(p + c8*8);
        const u32* uw = (const u32*)&u;
        u32 ow[4];
#pragma unroll
        for (int h2 = 0; h2 < 4; ++h2) {
          const int cidx = c8*8 + h2*2;
          float f0 = bf2f((u16)(uw[h2] & 0xFFFFu));
          float f1 = bf2f((u16)(uw[h2] >> 16));
          f0 = fmaxf(f0*sA[cidx]   + sB[cidx],   0.f);
          f1 = fmaxf(f1*sA[cidx+1] + sB[cidx+1], 0.f);
          ow[h2] = (u32)f2bf(f0) | ((u32)f2bf(f1) << 16);
        }
        pk = make_uint4(ow[0], ow[1], ow[2], ow[3]);
      }
      *(uint4*)(L + ((lb + (u32)(c8*16)) ^ sw)) = pk;
    }
  }
  __syncthreads();

  u32 pre[2][3];
#pragma unroll
  for (int kb = 0; kb < 2; ++kb)
#pragma unroll
    for (int kw = 0; kw < 3; ++kw)
      pre[kb][kw] = ((u32)(l15*128 + kb*64 + qq*16)) ^ ((u32)((kw + l15) & 7) << 4);

  float ss = 0.f, sqs = 0.f;
  for (int m = 0; m < 16; ++m) {
    const int rm = m >> 2, cb = (m & 3) << 4;
    f32x4 acc = {0.f,0.f,0.f,0.f};
#pragma unroll
    for (int kh = 0; kh < 3; ++kh) {
      const u32 rb = (u32)(((rm + kh)*SC + cb)*128);
#pragma unroll
      for (int kw = 0; kw < 3; ++kw) {
        const short8 x0 = *(const short8*)(L + (rb + (u32)(kw*128) + pre[0][kw]));
        const short8 x1 = *(const short8*)(L + (rb + (u32)(kw*128) + pre[1][kw]));
        acc = __builtin_amdgcn_mfma_f32_16x16x32_bf16(x0, wf[kh*3+kw][0], acc, 0, 0, 0);
        acc = __builtin_amdgcn_mfma_f32_16x16x32_bf16(x1, wf[kh*3+kw][1], acc, 0, 0, 0);
      }
    }
#pragma unroll
    for (int r = 0; r < 4; ++r) {
      float a = acc[r] + b2v;
      acc[r] = a;
      ss += a; sqs += a*a;
    }
    {
      const int gw = w0 + cb + qq*4;
      u16* dst = y2 + ((size_t)((nb*CC + coutA)*HH + (h0 + rm)))*WW + gw;
      uint2 pk;
      pk.x = (u32)f2bf(acc[0]) | ((u32)f2bf(acc[1]) << 16);
      pk.y = (u32)f2bf(acc[2]) | ((u32)f2bf(acc[3]) << 16);
      *(uint2*)dst = pk;
    }
  }
  ss  += __shfl_xor(ss, 16, 64);  ss  += __shfl_xor(ss, 32, 64);
  sqs += __shfl_xor(sqs, 16, 64); sqs += __shfl_xor(sqs, 32, 64);
  if (qq == 0) {
    ps2[(size_t)coutA*NBLK + bid] = ss;
    pq2[(size_t)coutA*NBLK + bid] = sqs;
  }
}

// ---------------- K5: out = relu(bn2(y2) + bnp(yp)), NCHW fp32 ----------------
__global__ __launch_bounds__(256) void k5(const u16* __restrict__ y2, const u16* __restrict__ yp,
    const float* __restrict__ A2, const float* __restrict__ B2,
    const float* __restrict__ Ap, const float* __restrict__ Bp,
    float* __restrict__ out)
{
  const size_t base = ((size_t)blockIdx.x*256 + threadIdx.x)*8;
  const int c = (int)((base >> 18) & 63);
  const float a2 = A2[c], b2 = B2[c], ap = Ap[c], bp = Bp[c];
  const uint4 u2 = *(const uint4*)(y2 + base);
  const uint4 up = *(const uint4*)(yp + base);
  const u32* m2 = (const u32*)&u2;
  const u32* mp = (const u32*)&up;
  float ov[8];
#pragma unroll
  for (int h2 = 0; h2 < 4; ++h2) {
    float a = bf2f((u16)(m2[h2] & 0xFFFFu));
    float b = bf2f((u16)(m2[h2] >> 16));
    float ra = bf2f((u16)(mp[h2] & 0xFFFFu));
    float rb = bf2f((u16)(mp[h2] >> 16));
    ov[h2*2]   = fmaxf(a*a2 + b2 + ra*ap + bp, 0.f);
    ov[h2*2+1] = fmaxf(b*a2 + b2 + rb*ap + bp, 0.f);
  }
  f32x4* o = (f32x4*)(out + base);
  o[0] = (f32x4){ov[0],ov[1],ov[2],ov[3]};
  o[1] = (f32x4){ov[4],ov[5],ov[6],ov[7]};
}

extern "C" void kernel_launch(void* const* d_in, const int* in_sizes, int n_in,
                              void* d_out, int out_size, void* d_ws, size_t ws_size,
                              hipStream_t stream)
{
  (void)in_sizes; (void)n_in; (void)out_size;
  const float* x   = (const float*)d_in[0];
  const float* w1  = (const float*)d_in[1];
  const float* b1  = (const float*)d_in[2];
  const float* g1  = (const float*)d_in[3];
  const float* be1 = (const float*)d_in[4];
  const float* w2  = (const float*)d_in[5];
  const float* b2  = (const float*)d_in[6];
  const float* g2  = (const float*)d_in[7];
  const float* be2 = (const float*)d_in[8];
  const float* wp  = (const float*)d_in[9];
  const float* bp  = (const float*)d_in[10];
  const float* gp  = (const float*)d_in[11];
  const float* bep = (const float*)d_in[12];

  const size_t TEN = (size_t)2*CC*PLANE;          // 33,554,432 elements
  const size_t need = TEN*2*3 + (size_t)6*CC*NBLK*4 + 6*CC*4;
  if (ws_size < need) return;  // workspace too small: fail loudly (wrong output)

  char* ws = (char*)d_ws;
  u16* y1 = (u16*)ws;                 // NHWC bf16
  u16* yp = (u16*)(ws + TEN*2);       // NCHW bf16
  u16* y2 = (u16*)(ws + TEN*4);       // NCHW bf16
  u16* xh = y2;                       // NHWC bf16 (aliases y2: dead before k3 writes y2)
  float* ps1 = (float*)(ws + TEN*6);
  float* pq1 = ps1 + (size_t)CC*NBLK;
  float* psp = pq1 + (size_t)CC*NBLK;
  float* pqp = psp + (size_t)CC*NBLK;
  float* ps2 = pqp + (size_t)CC*NBLK;
  float* pq2 = ps2 + (size_t)CC*NBLK;
  float* A1  = pq2 + (size_t)CC*NBLK;
  float* B1  = A1 + CC;
  float* Ap  = B1 + CC;
  float* Bp  = Ap + CC;
  float* A2  = Bp + CC;
  float* B2c = A2 + CC;

  dim3 grid(WW/TW, HH/TH, 2);
  k0<<<dim3(2, HH, 2), 256, 0, stream>>>(x, xh);
  k1<<<grid, 256, 0, stream>>>(xh, w1, b1, wp, bp, y1, yp, ps1, pq1, psp, pqp);
  kfin2<<<2*CC, 256, 0, stream>>>(ps1, pq1, g1, be1, A1, B1,
                                  psp, pqp, gp, bep, Ap, Bp);
  k3<<<grid, 256, 0, stream>>>(y1, w2, b2, A1, B1, y2, ps2, pq2);
  kfin2<<<CC, 256, 0, stream>>>(ps2, pq2, g2, be2, A2, B2c,
                                ps2, pq2, g2, be2, A2, B2c);
  k5<<<(int)(TEN/(256*8)), 256, 0, stream>>>(y2, yp, A2, B2c, Ap, Bp, (float*)d_out);
}

// Round 3
// 302.409 us; speedup vs baseline: 1.1720x; 1.0279x over previous
//
#include <hip/hip_runtime.h>
#include <hip/hip_bf16.h>
#include <stdint.h>

typedef short short8 __attribute__((ext_vector_type(8)));
typedef float f32x4 __attribute__((ext_vector_type(4)));
typedef float f32x16 __attribute__((ext_vector_type(16)));
typedef unsigned int u32;
typedef unsigned short u16;

#define HH 512
#define WW 512
#define CC 64
#define PLANE (HH*WW)
#define NSTATF 524288.0f

// kconv geometry
#define KTW 32            // output cols per block
#define SCL 34            // staged cols (1 halo each side)
#define HSTR 592          // half (8-ch) stride bytes within slot
#define KBSTR 1184        // kb stride bytes
#define SLOTB 4736        // row-slot bytes
#define NSLOT 14
#define RINGB (NSLOT*SLOTB)   // 66304
#define BOUNCEB 16384
#define NBC 1024          // conv stat partials (256 blocks * 4 row-waves)
#define NBP 4096          // proj stat partials (2048 blocks * 2)
#define TS 258            // k0 transpose tile stride (u16)

__device__ __forceinline__ u16 f2bf(float f) {
  __hip_bfloat16 h = __float2bfloat16(f);
  return __builtin_bit_cast(u16, h);
}
__device__ __forceinline__ u32 pk2bf(float a, float b) {
  return (u32)f2bf(a) | ((u32)f2bf(b) << 16);
}
__device__ __forceinline__ float bf2f(u16 u) {
  u32 x = ((u32)u) << 16;
  return __builtin_bit_cast(float, x);
}

// ---------------- kprep: build bf16 MFMA A-fragment buffers ----------------
// conv frag f=(ct*36+tap*4+kb): [f][lane][8] ; lane: cout=ct*32+(l&31), k=(l>>5)*8+r
__global__ __launch_bounds__(512) void kprep(const float* __restrict__ w1,
    const float* __restrict__ w2, const float* __restrict__ wp,
    u16* __restrict__ wb1, u16* __restrict__ wb2, u16* __restrict__ wbp)
{
  const int id = blockIdx.x*512 + threadIdx.x;
  const int lane = id & 63;
  if (id < 9216) {
    const float* w = (id < 4608) ? w1 : w2;
    u16* o = (id < 4608) ? wb1 : wb2;
    const int fid = (id < 4608) ? (id >> 6) : ((id - 4608) >> 6);  // 0..71
    const int ct = fid / 36, rem = fid % 36;
    const int tap = rem >> 2, kb = rem & 3;
    const int cout = ct*32 + (lane & 31);
    const int cinb = kb*16 + (lane >> 5)*8;
    u32 ow[4];
#pragma unroll
    for (int p = 0; p < 4; ++p) {
      float a = w[(size_t)(cout*64 + cinb + p*2    )*9 + tap];
      float b = w[(size_t)(cout*64 + cinb + p*2 + 1)*9 + tap];
      ow[p] = pk2bf(a, b);
    }
    *(uint4*)(o + ((size_t)fid*64 + lane)*8) = make_uint4(ow[0],ow[1],ow[2],ow[3]);
  } else if (id < 9728) {
    const int fid = (id - 9216) >> 6;     // 0..7
    const int ct = fid >> 2, kb = fid & 3;
    const int cout = ct*32 + (lane & 31);
    const int cinb = kb*16 + (lane >> 5)*8;
    u32 ow[4];
#pragma unroll
    for (int p = 0; p < 4; ++p)
      ow[p] = pk2bf(wp[cout*64 + cinb + p*2], wp[cout*64 + cinb + p*2 + 1]);
    *(uint4*)(wbp + ((size_t)fid*64 + lane)*8) = make_uint4(ow[0],ow[1],ow[2],ow[3]);
  }
}

// ---------------- k0: NCHW fp32 -> NHWC bf16 transpose + 1x1 projection ----------------
__global__ __launch_bounds__(256) void k0(const float* __restrict__ x,
    const u16* __restrict__ wbp, const float* __restrict__ bp,
    u16* __restrict__ xh, u16* __restrict__ yp,
    float* __restrict__ psp, float* __restrict__ pqp)
{
  __shared__ __align__(16) u16 T[CC*TS];
  __shared__ __align__(16) char B2[32768];
  const int tid = threadIdx.x;
  const int lane = tid & 63, wv = tid >> 6;
  const int ct = wv & 1, tg = wv >> 1;
  const int wt = blockIdx.x, h = blockIdx.y, n = blockIdx.z;
  const int w0 = wt*256;
  const int bid0 = (n*HH + h)*2 + wt;

  short8 wpf[4];
#pragma unroll
  for (int kb = 0; kb < 4; ++kb)
    wpf[kb] = *(const short8*)(wbp + ((size_t)(ct*4 + kb)*64 + lane)*8);
  float bv[16];
#pragma unroll
  for (int r = 0; r < 16; ++r)
    bv[r] = bp[ct*32 + (r&3) + 8*(r>>2) + 4*(lane>>5)];

  // phase A: coalesced fp32 read -> [c][w] bf16 tile
  const float* xp = x + (size_t)n*CC*PLANE + (size_t)h*WW + w0;
#pragma unroll
  for (int it = 0; it < 16; ++it) {
    const int j = it*256 + tid;
    const int c = j >> 6, w4 = (j & 63) << 2;
    const f32x4 v = *(const f32x4*)(xp + (size_t)c*PLANE + w4);
    u16* tp = T + c*TS + w4;
    *(u32*)(tp)     = pk2bf(v[0], v[1]);
    *(u32*)(tp + 2) = pk2bf(v[2], v[3]);
  }
  __syncthreads();
  // phase B: NHWC uint4 -> global xh + LDS B2 (swizzled)
  u16* op = xh + ((size_t)(n*HH + h)*WW + w0)*CC;
#pragma unroll
  for (int it = 0; it < 8; ++it) {
    const int j = it*256 + tid;
    const int w = j >> 3, c8 = j & 7;
    u32 ow[4];
#pragma unroll
    for (int p2 = 0; p2 < 4; ++p2) {
      const u32 lo = T[(c8*8 + p2*2    )*TS + w];
      const u32 hi = T[(c8*8 + p2*2 + 1)*TS + w];
      ow[p2] = lo | (hi << 16);
    }
    const uint4 pk = make_uint4(ow[0], ow[1], ow[2], ow[3]);
    *(uint4*)(op + (size_t)w*CC + c8*8) = pk;
    *(uint4*)(B2 + (((u32)(w*128 + c8*16)) ^ (((u32)(w & 7)) << 4))) = pk;
  }
  __syncthreads();
  // phase C: projection MFMA (4 tiles of 32 positions per wave)
  f32x16 pa[4];
  float s[16], q[16];
#pragma unroll
  for (int r = 0; r < 16; ++r) { s[r] = 0.f; q[r] = 0.f; }
#pragma unroll
  for (int ti = 0; ti < 4; ++ti) {
    const int tl = tg + ti*2;
    const int pos = tl*32 + (lane & 31);
    f32x16 acc;
#pragma unroll
    for (int r = 0; r < 16; ++r) acc[r] = 0.f;
#pragma unroll
    for (int kb = 0; kb < 4; ++kb) {
      const short8 bf = *(const short8*)(B2 +
          (((u32)(pos*128 + kb*32 + (lane>>5)*16)) ^ (((u32)(pos & 7)) << 4)));
      acc = __builtin_amdgcn_mfma_f32_32x32x16_bf16(wpf[kb], bf, acc, 0, 0, 0);
    }
#pragma unroll
    for (int r = 0; r < 16; ++r) {
      const float v = acc[r] + bv[r];
      pa[ti][r] = v; s[r] += v; q[r] = fmaf(v, v, q[r]);
    }
  }
  __syncthreads();
  // phase D: bounce proj outputs into B2 as swizzled [pos][c] bf16
#pragma unroll
  for (int ti = 0; ti < 4; ++ti) {
    const int tl = tg + ti*2;
    const int pos = tl*32 + (lane & 31);
    const int rp[8] = {0,2,8,10,16,18,24,26};
#pragma unroll
    for (int p = 0; p < 8; ++p) {
      const int co = ct*32 + 4*(lane>>5) + rp[p];
      *(u32*)(B2 + (((u32)(pos*128 + co*2)) ^ (((u32)(pos & 7)) << 4))) =
          pk2bf(pa[ti][p*2], pa[ti][p*2+1]);
    }
  }
  __syncthreads();
  // phase E: coalesced yp write
  u16* opp = yp + ((size_t)(n*HH + h)*WW + w0)*CC;
#pragma unroll
  for (int it = 0; it < 8; ++it) {
    const int j = it*256 + tid;
    const int pos = j >> 3, qi = j & 7;
    const uint4 v = *(const uint4*)(B2 +
        (((u32)(pos*128 + qi*16)) ^ (((u32)(pos & 7)) << 4)));
    *(uint4*)((char*)opp + (size_t)pos*128 + qi*16) = v;
  }
  // proj stats partials
#pragma unroll
  for (int d = 1; d <= 16; d <<= 1) {
#pragma unroll
    for (int r = 0; r < 16; ++r) {
      s[r] += __shfl_xor(s[r], d, 64);
      q[r] += __shfl_xor(q[r], d, 64);
    }
  }
  if ((lane & 31) == 0) {
#pragma unroll
    for (int r = 0; r < 16; ++r) {
      const int co = ct*32 + (r&3) + 8*(r>>2) + 4*(lane>>5);
      psp[(size_t)co*NBP + bid0*2 + tg] = s[r];
      pqp[(size_t)co*NBP + bid0*2 + tg] = q[r];
    }
  }
}

// ---------------- kconv: 3x3 conv, 32x32x16 MFMA, sliding ring ----------------
template<bool BNS>
__global__ __launch_bounds__(512, 2) void kconv(const u16* __restrict__ in,
    const u16* __restrict__ wb, const float* __restrict__ bias,
    const float* __restrict__ As, const float* __restrict__ Bs,
    u16* __restrict__ out, float* __restrict__ ps, float* __restrict__ pq)
{
  __shared__ __align__(16) char LB[RINGB + BOUNCEB + 512];
  float* sA = (float*)(LB + RINGB + BOUNCEB);
  float* sB = sA + 64;
  const int tid = threadIdx.x;
  const int lane = tid & 63, wv = tid >> 6;
  const int ct = wv & 1, ro = wv >> 1;
  const int wt = blockIdx.x, hs = blockIdx.y, n = blockIdx.z;
  const int w0 = wt*KTW, h0 = hs*64;
  const int bid = (n*8 + hs)*16 + wt;

  if (BNS) {
    if (tid < 64) { sA[tid] = As[tid]; sB[tid] = Bs[tid]; }
    __syncthreads();
  }

  short8 wfr[36];
#pragma unroll
  for (int f = 0; f < 36; ++f)
    wfr[f] = *(const short8*)(wb + ((size_t)(ct*36 + f)*64 + lane)*8);
  float bv[16];
#pragma unroll
  for (int r = 0; r < 16; ++r)
    bv[r] = bias[ct*32 + (r&3) + 8*(r>>2) + 4*(lane>>5)];
  float s[16], q[16];
#pragma unroll
  for (int r = 0; r < 16; ++r) { s[r] = 0.f; q[r] = 0.f; }

  const u16* inb = in + (size_t)n*PLANE*CC;
  const u32 lt = (u32)((lane & 31)*16 + (lane >> 5)*HSTR);

  // helpers (inlined by hand via lambdas)
  auto ld_one = [&](int j, int cl, int c8) -> uint4 {
    const int gh = h0 - 1 + j, gw = w0 - 1 + cl;
    if (((u32)gh < (u32)HH) && ((u32)gw < (u32)WW))
      return *(const uint4*)(inb + ((size_t)gh*WW + gw)*CC + c8*8);
    return make_uint4(0u,0u,0u,0u);
  };
  auto st_one = [&](int slot, int cl, int c8, uint4 v) {
    if (BNS) {
      const u32* uw = (const u32*)&v;
      u32 ow[4];
      const int cb = c8*8;
#pragma unroll
      for (int h2 = 0; h2 < 4; ++h2) {
        float f0 = fmaxf(bf2f((u16)(uw[h2] & 0xFFFFu)) * sA[cb+h2*2]   + sB[cb+h2*2],   0.f);
        float f1 = fmaxf(bf2f((u16)(uw[h2] >> 16))     * sA[cb+h2*2+1] + sB[cb+h2*2+1], 0.f);
        ow[h2] = pk2bf(f0, f1);
      }
      v = make_uint4(ow[0],ow[1],ow[2],ow[3]);
    }
    *(uint4*)(LB + (size_t)slot*SLOTB + (c8>>1)*KBSTR + (c8&1)*HSTR + cl*16) = v;
  };

  // prologue: stage rows j = 0..13
#pragma unroll
  for (int i = 0; i < 8; ++i) {
    const int idx = i*512 + tid;
    if (idx < 14*272) {
      const int jj = idx / 272, rem = idx - jj*272;
      const int cl = rem >> 3, c8 = rem & 7;
      st_one(jj, cl, c8, ld_one(jj, cl, c8));
    }
  }
  __syncthreads();

  int sj = ro % NSLOT;        // slot of j = 4g+ro
  int s4 = 0;                 // (4g) % NSLOT
  for (int g = 0; g < 16; ++g) {
    const bool dostage = (g <= 12);
    const int jb = 4*g + 14;
    uint4 st0, st1, st2;
    if (dostage) {
      { const int idx = tid;      const int jj = idx/272, rem = idx - jj*272;
        st0 = ld_one(jb + jj, rem >> 3, rem & 7); }
      { const int idx = 512 + tid; const int jj = idx/272, rem = idx - jj*272;
        st1 = ld_one(jb + jj, rem >> 3, rem & 7); }
      if (tid < 64) { const int idx = 1024 + tid; const int jj = idx/272, rem = idx - jj*272;
        st2 = ld_one(jb + jj, rem >> 3, rem & 7); }
    }

    // compute: one output row per wave, 36 MFMAs
    int sl0 = sj;
    int sl1 = sl0 + 1; if (sl1 >= NSLOT) sl1 -= NSLOT;
    int sl2 = sl1 + 1; if (sl2 >= NSLOT) sl2 -= NSLOT;
    f32x16 acc;
#pragma unroll
    for (int r = 0; r < 16; ++r) acc[r] = 0.f;
    {
      const char* b0 = LB + (size_t)sl0*SLOTB + lt;
      const char* b1 = LB + (size_t)sl1*SLOTB + lt;
      const char* b2 = LB + (size_t)sl2*SLOTB + lt;
#pragma unroll
      for (int kb = 0; kb < 4; ++kb) {
#pragma unroll
        for (int kw = 0; kw < 3; ++kw) {
          const short8 x0 = *(const short8*)(b0 + kb*KBSTR + kw*16);
          acc = __builtin_amdgcn_mfma_f32_32x32x16_bf16(wfr[(0*3+kw)*4+kb], x0, acc, 0,0,0);
        }
#pragma unroll
        for (int kw = 0; kw < 3; ++kw) {
          const short8 x1 = *(const short8*)(b1 + kb*KBSTR + kw*16);
          acc = __builtin_amdgcn_mfma_f32_32x32x16_bf16(wfr[(1*3+kw)*4+kb], x1, acc, 0,0,0);
        }
#pragma unroll
        for (int kw = 0; kw < 3; ++kw) {
          const short8 x2 = *(const short8*)(b2 + kb*KBSTR + kw*16);
          acc = __builtin_amdgcn_mfma_f32_32x32x16_bf16(wfr[(2*3+kw)*4+kb], x2, acc, 0,0,0);
        }
      }
    }
    // bias + stats + bounce write
    {
      const int pos = lane & 31;
      const int rp[8] = {0,2,8,10,16,18,24,26};
      float av[16];
#pragma unroll
      for (int r = 0; r < 16; ++r) {
        const float v = acc[r] + bv[r];
        av[r] = v; s[r] += v; q[r] = fmaf(v, v, q[r]);
      }
#pragma unroll
      for (int p = 0; p < 8; ++p) {
        const int co = ct*32 + 4*(lane>>5) + rp[p];
        *(u32*)(LB + RINGB + ro*4096 +
            (((u32)(pos*128 + co*2)) ^ (((u32)(pos & 7)) << 4))) = pk2bf(av[p*2], av[p*2+1]);
      }
    }
    __syncthreads();
    // bounce readout -> coalesced NHWC global write
    {
      const int rowi = tid >> 7, tt = tid & 127;
      const int rpos = tt >> 2, qb = (tt & 3)*32;
      const char* bb = LB + RINGB + rowi*4096;
      const u32 a0 = ((u32)(rpos*128 + qb)) ^ (((u32)(rpos & 7)) << 4);
      const uint4 v0 = *(const uint4*)(bb + a0);
      const uint4 v1 = *(const uint4*)(bb + (a0 ^ 16u));
      const int ghr = h0 + g*4 + rowi;
      char* dst = (char*)out + ((size_t)((n*HH + ghr)*WW + w0 + rpos))*128 + qb;
      *(uint4*)dst = v0;
      *(uint4*)(dst + 16) = v1;
    }
    // ring writes of prefetched batch
    if (dostage) {
      { const int idx = tid;      const int jj = idx/272, rem = idx - jj*272;
        int sl = s4 + jj; if (sl >= NSLOT) sl -= NSLOT;
        st_one(sl, rem >> 3, rem & 7, st0); }
      { const int idx = 512 + tid; const int jj = idx/272, rem = idx - jj*272;
        int sl = s4 + jj; if (sl >= NSLOT) sl -= NSLOT;
        st_one(sl, rem >> 3, rem & 7, st1); }
      if (tid < 64) { const int idx = 1024 + tid; const int jj = idx/272, rem = idx - jj*272;
        int sl = s4 + jj; if (sl >= NSLOT) sl -= NSLOT;
        st_one(sl, rem >> 3, rem & 7, st2); }
    }
    __syncthreads();
    sj += 4; if (sj >= NSLOT) sj -= NSLOT;
    s4 += 4; if (s4 >= NSLOT) s4 -= NSLOT;
  }

  // stats partials
#pragma unroll
  for (int d = 1; d <= 16; d <<= 1) {
#pragma unroll
    for (int r = 0; r < 16; ++r) {
      s[r] += __shfl_xor(s[r], d, 64);
      q[r] += __shfl_xor(q[r], d, 64);
    }
  }
  if ((lane & 31) == 0) {
#pragma unroll
    for (int r = 0; r < 16; ++r) {
      const int co = ct*32 + (r&3) + 8*(r>>2) + 4*(lane>>5);
      ps[(size_t)co*NBC + bid*4 + ro] = s[r];
      pq[(size_t)co*NBC + bid*4 + ro] = q[r];
    }
  }
}

// ---------------- kfin2: finalize two BN stat sets ----------------
__global__ __launch_bounds__(256) void kfin2(
    const float* __restrict__ psA, const float* __restrict__ pqA,
    const float* __restrict__ gA, const float* __restrict__ beA,
    float* __restrict__ AA, float* __restrict__ BA, int cntA,
    const float* __restrict__ psB, const float* __restrict__ pqB,
    const float* __restrict__ gB, const float* __restrict__ beB,
    float* __restrict__ AB, float* __restrict__ BB, int cntB)
{
  const int blk = blockIdx.x;
  const bool second = blk >= 64;
  const int c = blk & 63;
  const float* psx = second ? psB : psA;
  const float* pqx = second ? pqB : pqA;
  const float* g  = second ? gB  : gA;
  const float* be = second ? beB : beA;
  float* A  = second ? AB : AA;
  float* Bc = second ? BB : BA;
  const int cnt = second ? cntB : cntA;

  const int t = threadIdx.x;
  float sv = 0.f, s2 = 0.f;
  const float* pr = psx + (size_t)c*cnt;
  const float* qr = pqx + (size_t)c*cnt;
  for (int k = t; k < cnt; k += 256) { sv += pr[k]; s2 += qr[k]; }
#pragma unroll
  for (int d = 1; d < 64; d <<= 1) { sv += __shfl_xor(sv, d, 64); s2 += __shfl_xor(s2, d, 64); }
  __shared__ float as_[4], aq_[4];
  if ((t & 63) == 0) { as_[t >> 6] = sv; aq_[t >> 6] = s2; }
  __syncthreads();
  if (t == 0) {
    sv = as_[0] + as_[1] + as_[2] + as_[3];
    s2 = aq_[0] + aq_[1] + aq_[2] + aq_[3];
    const float mean = sv / NSTATF;
    const float var = s2 / NSTATF - mean*mean;
    const float istd = rsqrtf(var + 1e-5f);
    const float a = g[c] * istd;
    A[c] = a;
    Bc[c] = be[c] - mean * a;
  }
}

// ---------------- k5: out = relu(bn2(y2) + bnp(yp)), NHWC -> NCHW fp32 ----------------
__global__ __launch_bounds__(256) void k5(const u16* __restrict__ y2, const u16* __restrict__ yp,
    const float* __restrict__ A2, const float* __restrict__ B2c,
    const float* __restrict__ Ap, const float* __restrict__ Bp,
    float* __restrict__ outp)
{
  __shared__ float T[CC*257];
  __shared__ float cA2[64], cB2[64], cAp[64], cBp[64];
  const int tid = threadIdx.x;
  const int wt = blockIdx.x, h = blockIdx.y, n = blockIdx.z;
  const int w0 = wt*256;
  if (tid < 64) { cA2[tid] = A2[tid]; cB2[tid] = B2c[tid]; cAp[tid] = Ap[tid]; cBp[tid] = Bp[tid]; }
  __syncthreads();
  const u16* p2 = y2 + ((size_t)(n*HH + h)*WW + w0)*CC;
  const u16* pp = yp + ((size_t)(n*HH + h)*WW + w0)*CC;
#pragma unroll
  for (int it = 0; it < 8; ++it) {
    const int j = it*256 + tid;
    const int w = j >> 3, c8 = j & 7;
    const uint4 u2 = *(const uint4*)(p2 + (size_t)w*CC + c8*8);
    const uint4 up = *(const uint4*)(pp + (size_t)w*CC + c8*8);
    const u32* m2 = (const u32*)&u2;
    const u32* mp = (const u32*)&up;
#pragma unroll
    for (int h2 = 0; h2 < 4; ++h2) {
      const int c = c8*8 + h2*2;
      const float a = bf2f((u16)(m2[h2] & 0xFFFFu)), b = bf2f((u16)(m2[h2] >> 16));
      const float ra = bf2f((u16)(mp[h2] & 0xFFFFu)), rb = bf2f((u16)(mp[h2] >> 16));
      T[(c    )*257 + w] = fmaxf(a*cA2[c]   + cB2[c]   + ra*cAp[c]   + cBp[c],   0.f);
      T[(c + 1)*257 + w] = fmaxf(b*cA2[c+1] + cB2[c+1] + rb*cAp[c+1] + cBp[c+1], 0.f);
    }
  }
  __syncthreads();
  const int c = tid >> 2, wq = tid & 3;
  float* orow = outp + ((size_t)((n*CC + c)*HH + h))*WW + w0 + wq*64;
  const float* tr = T + c*257 + wq*64;
#pragma unroll
  for (int i = 0; i < 16; ++i) {
    f32x4 v;
#pragma unroll
    for (int l = 0; l < 4; ++l) v[l] = tr[i*4 + l];
    *(f32x4*)(orow + i*4) = v;
  }
}

extern "C" void kernel_launch(void* const* d_in, const int* in_sizes, int n_in,
                              void* d_out, int out_size, void* d_ws, size_t ws_size,
                              hipStream_t stream)
{
  (void)in_sizes; (void)n_in; (void)out_size;
  const float* x   = (const float*)d_in[0];
  const float* w1  = (const float*)d_in[1];
  const float* b1  = (const float*)d_in[2];
  const float* g1  = (const float*)d_in[3];
  const float* be1 = (const float*)d_in[4];
  const float* w2  = (const float*)d_in[5];
  const float* b2  = (const float*)d_in[6];
  const float* g2  = (const float*)d_in[7];
  const float* be2 = (const float*)d_in[8];
  const float* wp  = (const float*)d_in[9];
  const float* bp  = (const float*)d_in[10];
  const float* gp  = (const float*)d_in[11];
  const float* bep = (const float*)d_in[12];

  const size_t TENB = (size_t)2*CC*PLANE*2;   // one bf16 tensor: 67,108,864 B
  char* ws = (char*)d_ws;
  u16* bufA = (u16*)ws;                    // xh, later y2
  u16* bufB = (u16*)(ws + TENB);           // y1
  u16* bufC = (u16*)(ws + TENB*2);         // yp
  char* aux = ws + TENB*3;
  u16* wb1 = (u16*)aux;                              // 73728 B
  u16* wb2 = (u16*)(aux + 73728);                    // 73728 B
  u16* wbp = (u16*)(aux + 147456);                   // 8192 B
  float* ps1 = (float*)(aux + 155648);               // 64*1024*4
  float* pq1 = ps1 + 64*NBC;
  float* ps2 = pq1 + 64*NBC;
  float* pq2 = ps2 + 64*NBC;
  float* psp = pq2 + 64*NBC;                         // 64*4096*4
  float* pqp = psp + 64*NBP;
  float* A1  = pqp + 64*NBP;
  float* B1  = A1 + 64;
  float* A2  = B1 + 64;
  float* B2c = A2 + 64;
  float* Ap  = B2c + 64;
  float* Bp  = Ap + 64;
  const size_t need = (size_t)(Bp + 64 - (float*)ws) * 4;
  if (ws_size < need) return;

  kprep<<<19, 512, 0, stream>>>(w1, w2, wp, wb1, wb2, wbp);
  k0<<<dim3(2, HH, 2), 256, 0, stream>>>(x, wbp, bp, bufA, bufC, psp, pqp);
  kconv<false><<<dim3(16, 8, 2), 512, 0, stream>>>(bufA, wb1, b1, nullptr, nullptr,
                                                   bufB, ps1, pq1);
  kfin2<<<128, 256, 0, stream>>>(ps1, pq1, g1, be1, A1, B1, NBC,
                                 psp, pqp, gp, bep, Ap, Bp, NBP);
  kconv<true><<<dim3(16, 8, 2), 512, 0, stream>>>(bufB, wb2, b2, A1, B1,
                                                  bufA, ps2, pq2);
  kfin2<<<64, 256, 0, stream>>>(ps2, pq2, g2, be2, A2, B2c, NBC,
                                ps2, pq2, g2, be2, A2, B2c, NBC);
  k5<<<dim3(2, HH, 2), 256, 0, stream>>>(bufA, bufC, A2, B2c, Ap, Bp, (float*)d_out);
}

// Round 4
// 271.834 us; speedup vs baseline: 1.3039x; 1.1125x over previous
//
#include <hip/hip_runtime.h>
#include <hip/hip_bf16.h>
#include <stdint.h>

typedef short short8 __attribute__((ext_vector_type(8)));
typedef float f32x4 __attribute__((ext_vector_type(4)));
typedef float f32x16 __attribute__((ext_vector_type(16)));
typedef unsigned int u32;
typedef unsigned short u16;

#define HH 512
#define WW 512
#define CC 64
#define PLANE (HH*WW)
#define NSTATF 524288.0f

// kconv geometry (256-thread version)
#define KTW 32            // output cols per block
#define HSTR 592          // half (8-ch) stride bytes within slot
#define KBSTR 1184        // kb stride bytes
#define SLOTB 4736        // row-slot bytes
#define NSLOT 8
#define RINGB (NSLOT*SLOTB)   // 37888
#define BOUNCEB 8192
#define NBC 1024          // conv stat partials (512 blocks * 2 row-waves)
#define NBP 4096          // proj stat partials (2048 blocks * 2)
#define TS 258            // k0 transpose tile stride (u16)
#define K5S 260           // k5 LDS tile stride (f32)

__device__ __forceinline__ u16 f2bf(float f) {
  __hip_bfloat16 h = __float2bfloat16(f);
  return __builtin_bit_cast(u16, h);
}
__device__ __forceinline__ u32 pk2bf(float a, float b) {
  return (u32)f2bf(a) | ((u32)f2bf(b) << 16);
}
__device__ __forceinline__ float bf2f(u16 u) {
  u32 x = ((u32)u) << 16;
  return __builtin_bit_cast(float, x);
}

// ---------------- kprep: build bf16 MFMA A-fragment buffers ----------------
// conv frag f=(ct*36+tap*4+kb): [f][lane][8] ; lane: cout=ct*32+(l&31), k=(l>>5)*8+r
__global__ __launch_bounds__(512) void kprep(const float* __restrict__ w1,
    const float* __restrict__ w2, const float* __restrict__ wp,
    u16* __restrict__ wb1, u16* __restrict__ wb2, u16* __restrict__ wbp)
{
  const int id = blockIdx.x*512 + threadIdx.x;
  const int lane = id & 63;
  if (id < 9216) {
    const float* w = (id < 4608) ? w1 : w2;
    u16* o = (id < 4608) ? wb1 : wb2;
    const int fid = (id < 4608) ? (id >> 6) : ((id - 4608) >> 6);  // 0..71
    const int ct = fid / 36, rem = fid % 36;
    const int tap = rem >> 2, kb = rem & 3;
    const int cout = ct*32 + (lane & 31);
    const int cinb = kb*16 + (lane >> 5)*8;
    u32 ow[4];
#pragma unroll
    for (int p = 0; p < 4; ++p) {
      float a = w[(size_t)(cout*64 + cinb + p*2    )*9 + tap];
      float b = w[(size_t)(cout*64 + cinb + p*2 + 1)*9 + tap];
      ow[p] = pk2bf(a, b);
    }
    *(uint4*)(o + ((size_t)fid*64 + lane)*8) = make_uint4(ow[0],ow[1],ow[2],ow[3]);
  } else if (id < 9728) {
    const int fid = (id - 9216) >> 6;     // 0..7
    const int ct = fid >> 2, kb = fid & 3;
    const int cout = ct*32 + (lane & 31);
    const int cinb = kb*16 + (lane >> 5)*8;
    u32 ow[4];
#pragma unroll
    for (int p = 0; p < 4; ++p)
      ow[p] = pk2bf(wp[cout*64 + cinb + p*2], wp[cout*64 + cinb + p*2 + 1]);
    *(uint4*)(wbp + ((size_t)fid*64 + lane)*8) = make_uint4(ow[0],ow[1],ow[2],ow[3]);
  }
}

// ---------------- k0: NCHW fp32 -> NHWC bf16 transpose + 1x1 projection ----------------
__global__ __launch_bounds__(256) void k0(const float* __restrict__ x,
    const u16* __restrict__ wbp, const float* __restrict__ bp,
    u16* __restrict__ xh, u16* __restrict__ yp,
    float* __restrict__ psp, float* __restrict__ pqp)
{
  __shared__ __align__(16) u16 T[CC*TS];
  __shared__ __align__(16) char B2[32768];
  const int tid = threadIdx.x;
  const int lane = tid & 63, wv = tid >> 6;
  const int ct = wv & 1, tg = wv >> 1;
  const int wt = blockIdx.x, h = blockIdx.y, n = blockIdx.z;
  const int w0 = wt*256;
  const int bid0 = (n*HH + h)*2 + wt;

  short8 wpf[4];
#pragma unroll
  for (int kb = 0; kb < 4; ++kb)
    wpf[kb] = *(const short8*)(wbp + ((size_t)(ct*4 + kb)*64 + lane)*8);
  float bv[16];
#pragma unroll
  for (int r = 0; r < 16; ++r)
    bv[r] = bp[ct*32 + (r&3) + 8*(r>>2) + 4*(lane>>5)];

  // phase A: coalesced fp32 read -> [c][w] bf16 tile
  const float* xp = x + (size_t)n*CC*PLANE + (size_t)h*WW + w0;
#pragma unroll
  for (int it = 0; it < 16; ++it) {
    const int j = it*256 + tid;
    const int c = j >> 6, w4 = (j & 63) << 2;
    const f32x4 v = *(const f32x4*)(xp + (size_t)c*PLANE + w4);
    u16* tp = T + c*TS + w4;
    *(u32*)(tp)     = pk2bf(v[0], v[1]);
    *(u32*)(tp + 2) = pk2bf(v[2], v[3]);
  }
  __syncthreads();
  // phase B: NHWC uint4 -> global xh + LDS B2 (swizzled)
  u16* op = xh + ((size_t)(n*HH + h)*WW + w0)*CC;
#pragma unroll
  for (int it = 0; it < 8; ++it) {
    const int j = it*256 + tid;
    const int w = j >> 3, c8 = j & 7;
    u32 ow[4];
#pragma unroll
    for (int p2 = 0; p2 < 4; ++p2) {
      const u32 lo = T[(c8*8 + p2*2    )*TS + w];
      const u32 hi = T[(c8*8 + p2*2 + 1)*TS + w];
      ow[p2] = lo | (hi << 16);
    }
    const uint4 pk = make_uint4(ow[0], ow[1], ow[2], ow[3]);
    *(uint4*)(op + (size_t)w*CC + c8*8) = pk;
    *(uint4*)(B2 + (((u32)(w*128 + c8*16)) ^ (((u32)(w & 7)) << 4))) = pk;
  }
  __syncthreads();
  // phase C: projection MFMA (4 tiles of 32 positions per wave)
  f32x16 pa[4];
  float s[16], q[16];
#pragma unroll
  for (int r = 0; r < 16; ++r) { s[r] = 0.f; q[r] = 0.f; }
#pragma unroll
  for (int ti = 0; ti < 4; ++ti) {
    const int tl = tg + ti*2;
    const int pos = tl*32 + (lane & 31);
    f32x16 acc;
#pragma unroll
    for (int r = 0; r < 16; ++r) acc[r] = 0.f;
#pragma unroll
    for (int kb = 0; kb < 4; ++kb) {
      const short8 bf = *(const short8*)(B2 +
          (((u32)(pos*128 + kb*32 + (lane>>5)*16)) ^ (((u32)(pos & 7)) << 4)));
      acc = __builtin_amdgcn_mfma_f32_32x32x16_bf16(wpf[kb], bf, acc, 0, 0, 0);
    }
#pragma unroll
    for (int r = 0; r < 16; ++r) {
      const float v = acc[r] + bv[r];
      pa[ti][r] = v; s[r] += v; q[r] = fmaf(v, v, q[r]);
    }
  }
  __syncthreads();
  // phase D: bounce proj outputs into B2 as swizzled [pos][c] bf16
#pragma unroll
  for (int ti = 0; ti < 4; ++ti) {
    const int tl = tg + ti*2;
    const int pos = tl*32 + (lane & 31);
    const int rp[8] = {0,2,8,10,16,18,24,26};
#pragma unroll
    for (int p = 0; p < 8; ++p) {
      const int co = ct*32 + 4*(lane>>5) + rp[p];
      *(u32*)(B2 + (((u32)(pos*128 + co*2)) ^ (((u32)(pos & 7)) << 4))) =
          pk2bf(pa[ti][p*2], pa[ti][p*2+1]);
    }
  }
  __syncthreads();
  // phase E: coalesced yp write
  u16* opp = yp + ((size_t)(n*HH + h)*WW + w0)*CC;
#pragma unroll
  for (int it = 0; it < 8; ++it) {
    const int j = it*256 + tid;
    const int pos = j >> 3, qi = j & 7;
    const uint4 v = *(const uint4*)(B2 +
        (((u32)(pos*128 + qi*16)) ^ (((u32)(pos & 7)) << 4)));
    *(uint4*)((char*)opp + (size_t)pos*128 + qi*16) = v;
  }
  // proj stats partials
#pragma unroll
  for (int d = 1; d <= 16; d <<= 1) {
#pragma unroll
    for (int r = 0; r < 16; ++r) {
      s[r] += __shfl_xor(s[r], d, 64);
      q[r] += __shfl_xor(q[r], d, 64);
    }
  }
  if ((lane & 31) == 0) {
#pragma unroll
    for (int r = 0; r < 16; ++r) {
      const int co = ct*32 + (r&3) + 8*(r>>2) + 4*(lane>>5);
      psp[(size_t)co*NBP + bid0*2 + tg] = s[r];
      pqp[(size_t)co*NBP + bid0*2 + tg] = q[r];
    }
  }
}

// ---------------- kconv: 3x3 conv, 32x32x16 MFMA, sliding ring, 256 thr ----------------
template<bool BNS>
__global__ __launch_bounds__(256, 1) void kconv(const u16* __restrict__ in,
    const u16* __restrict__ wb, const float* __restrict__ bias,
    const float* __restrict__ As, const float* __restrict__ Bs,
    u16* __restrict__ out, float* __restrict__ ps, float* __restrict__ pq)
{
  __shared__ __align__(16) char LB[RINGB + BOUNCEB + 512];
  float* sA = (float*)(LB + RINGB + BOUNCEB);
  float* sB = sA + 64;
  const int tid = threadIdx.x;
  const int lane = tid & 63, wv = tid >> 6;
  const int ct = wv & 1, ro = wv >> 1;        // 2 ct x 2 row-waves
  const int wt = blockIdx.x, hs = blockIdx.y, n = blockIdx.z;
  const int w0 = wt*KTW, h0 = hs*32;
  const int bid = (n*16 + hs)*16 + wt;        // 0..511

  if (BNS) {
    if (tid < 64) { sA[tid] = As[tid]; sB[tid] = Bs[tid]; }
    __syncthreads();
  }

  short8 wfr[36];
#pragma unroll
  for (int f = 0; f < 36; ++f)
    wfr[f] = *(const short8*)(wb + ((size_t)(ct*36 + f)*64 + lane)*8);
  float bv[16];
#pragma unroll
  for (int r = 0; r < 16; ++r)
    bv[r] = bias[ct*32 + (r&3) + 8*(r>>2) + 4*(lane>>5)];
  float s[16], q[16];
#pragma unroll
  for (int r = 0; r < 16; ++r) { s[r] = 0.f; q[r] = 0.f; }

  const u16* inb = in + (size_t)n*PLANE*CC;
  const u32 lt = (u32)((lane & 31)*16 + (lane >> 5)*HSTR);

  auto ld_one = [&](int j, int cl, int c8) -> uint4 {
    const int gh = h0 - 1 + j, gw = w0 - 1 + cl;
    if (((u32)gh < (u32)HH) && ((u32)gw < (u32)WW))
      return *(const uint4*)(inb + ((size_t)gh*WW + gw)*CC + c8*8);
    return make_uint4(0u,0u,0u,0u);
  };
  auto st_one = [&](int slot, int cl, int c8, uint4 v) {
    if (BNS) {
      const u32* uw = (const u32*)&v;
      u32 ow[4];
      const int cb = c8*8;
#pragma unroll
      for (int h2 = 0; h2 < 4; ++h2) {
        float f0 = fmaxf(bf2f((u16)(uw[h2] & 0xFFFFu)) * sA[cb+h2*2]   + sB[cb+h2*2],   0.f);
        float f1 = fmaxf(bf2f((u16)(uw[h2] >> 16))     * sA[cb+h2*2+1] + sB[cb+h2*2+1], 0.f);
        ow[h2] = pk2bf(f0, f1);
      }
      v = make_uint4(ow[0],ow[1],ow[2],ow[3]);
    }
    *(uint4*)(LB + (size_t)slot*SLOTB + (c8>>1)*KBSTR + (c8&1)*HSTR + cl*16) = v;
  };

  // prologue: stage rows j = 0..5 (slots 0..5)
#pragma unroll
  for (int i = 0; i < 7; ++i) {
    const int idx = i*256 + tid;
    if (idx < 6*272) {
      const int jj = idx / 272, rem = idx - jj*272;
      st_one(jj, rem >> 3, rem & 7, ld_one(jj, rem >> 3, rem & 7));
    }
  }
  __syncthreads();

  for (int g = 0; g < 16; ++g) {
    const bool dostage = (g <= 13);
    const int jb = 2*g + 6;
    uint4 st0, st1, st2;
    if (dostage) {
      { const int idx = tid;       const int jj = idx/272, rem = idx - jj*272;
        st0 = ld_one(jb + jj, rem >> 3, rem & 7); }
      { const int idx = 256 + tid; const int jj = idx/272, rem = idx - jj*272;
        st1 = ld_one(jb + jj, rem >> 3, rem & 7); }
      if (tid < 32) { const int idx = 512 + tid; const int jj = idx/272, rem = idx - jj*272;
        st2 = ld_one(jb + jj, rem >> 3, rem & 7); }
    }

    // compute: wave 'ro' does output local row r = 2g+ro; 36 MFMAs
    const int r = 2*g + ro;
    f32x16 acc;
#pragma unroll
    for (int rr = 0; rr < 16; ++rr) acc[rr] = 0.f;
    {
      const int sl0 = (r    ) & 7;
      const int sl1 = (r + 1) & 7;
      const int sl2 = (r + 2) & 7;
      const char* b0 = LB + (size_t)sl0*SLOTB + lt;
      const char* b1 = LB + (size_t)sl1*SLOTB + lt;
      const char* b2 = LB + (size_t)sl2*SLOTB + lt;
#pragma unroll
      for (int kb = 0; kb < 4; ++kb) {
#pragma unroll
        for (int kw = 0; kw < 3; ++kw) {
          const short8 x0 = *(const short8*)(b0 + kb*KBSTR + kw*16);
          acc = __builtin_amdgcn_mfma_f32_32x32x16_bf16(wfr[(0*3+kw)*4+kb], x0, acc, 0,0,0);
        }
#pragma unroll
        for (int kw = 0; kw < 3; ++kw) {
          const short8 x1 = *(const short8*)(b1 + kb*KBSTR + kw*16);
          acc = __builtin_amdgcn_mfma_f32_32x32x16_bf16(wfr[(1*3+kw)*4+kb], x1, acc, 0,0,0);
        }
#pragma unroll
        for (int kw = 0; kw < 3; ++kw) {
          const short8 x2 = *(const short8*)(b2 + kb*KBSTR + kw*16);
          acc = __builtin_amdgcn_mfma_f32_32x32x16_bf16(wfr[(2*3+kw)*4+kb], x2, acc, 0,0,0);
        }
      }
    }
    // bias + stats + bounce write
    {
      const int pos = lane & 31;
      const int rp[8] = {0,2,8,10,16,18,24,26};
      float av[16];
#pragma unroll
      for (int rr = 0; rr < 16; ++rr) {
        const float v = acc[rr] + bv[rr];
        av[rr] = v; s[rr] += v; q[rr] = fmaf(v, v, q[rr]);
      }
#pragma unroll
      for (int p = 0; p < 8; ++p) {
        const int co = ct*32 + 4*(lane>>5) + rp[p];
        *(u32*)(LB + RINGB + ro*4096 +
            (((u32)(pos*128 + co*2)) ^ (((u32)(pos & 7)) << 4))) = pk2bf(av[p*2], av[p*2+1]);
      }
    }
    __syncthreads();
    // bounce readout -> coalesced NHWC global write (2 rows x 4KB)
    {
      const int rowi = tid >> 7, tt = tid & 127;
      const int rpos = tt >> 2, qb = (tt & 3)*32;
      const char* bb = LB + RINGB + rowi*4096;
      const u32 a0 = ((u32)(rpos*128 + qb)) ^ (((u32)(rpos & 7)) << 4);
      const uint4 v0 = *(const uint4*)(bb + a0);
      const uint4 v1 = *(const uint4*)(bb + (a0 ^ 16u));
      const int ghr = h0 + 2*g + rowi;
      char* dst = (char*)out + ((size_t)((n*HH + ghr)*WW + w0 + rpos))*128 + qb;
      *(uint4*)dst = v0;
      *(uint4*)(dst + 16) = v1;
    }
    // ring writes of prefetched rows jb, jb+1
    if (dostage) {
      { const int idx = tid;       const int jj = idx/272, rem = idx - jj*272;
        st_one((jb + jj) & 7, rem >> 3, rem & 7, st0); }
      { const int idx = 256 + tid; const int jj = idx/272, rem = idx - jj*272;
        st_one((jb + jj) & 7, rem >> 3, rem & 7, st1); }
      if (tid < 32) { const int idx = 512 + tid; const int jj = idx/272, rem = idx - jj*272;
        st_one((jb + jj) & 7, rem >> 3, rem & 7, st2); }
    }
    __syncthreads();
  }

  // stats partials
#pragma unroll
  for (int d = 1; d <= 16; d <<= 1) {
#pragma unroll
    for (int rr = 0; rr < 16; ++rr) {
      s[rr] += __shfl_xor(s[rr], d, 64);
      q[rr] += __shfl_xor(q[rr], d, 64);
    }
  }
  if ((lane & 31) == 0) {
#pragma unroll
    for (int rr = 0; rr < 16; ++rr) {
      const int co = ct*32 + (rr&3) + 8*(rr>>2) + 4*(lane>>5);
      ps[(size_t)co*NBC + bid*2 + ro] = s[rr];
      pq[(size_t)co*NBC + bid*2 + ro] = q[rr];
    }
  }
}

// ---------------- kfin2: finalize two BN stat sets ----------------
__global__ __launch_bounds__(256) void kfin2(
    const float* __restrict__ psA, const float* __restrict__ pqA,
    const float* __restrict__ gA, const float* __restrict__ beA,
    float* __restrict__ AA, float* __restrict__ BA, int cntA,
    const float* __restrict__ psB, const float* __restrict__ pqB,
    const float* __restrict__ gB, const float* __restrict__ beB,
    float* __restrict__ AB, float* __restrict__ BB, int cntB)
{
  const int blk = blockIdx.x;
  const bool second = blk >= 64;
  const int c = blk & 63;
  const float* psx = second ? psB : psA;
  const float* pqx = second ? pqB : pqA;
  const float* g  = second ? gB  : gA;
  const float* be = second ? beB : beA;
  float* A  = second ? AB : AA;
  float* Bc = second ? BB : BA;
  const int cnt = second ? cntB : cntA;

  const int t = threadIdx.x;
  float sv = 0.f, s2 = 0.f;
  const float* pr = psx + (size_t)c*cnt;
  const float* qr = pqx + (size_t)c*cnt;
  for (int k = t; k < cnt; k += 256) { sv += pr[k]; s2 += qr[k]; }
#pragma unroll
  for (int d = 1; d < 64; d <<= 1) { sv += __shfl_xor(sv, d, 64); s2 += __shfl_xor(s2, d, 64); }
  __shared__ float as_[4], aq_[4];
  if ((t & 63) == 0) { as_[t >> 6] = sv; aq_[t >> 6] = s2; }
  __syncthreads();
  if (t == 0) {
    sv = as_[0] + as_[1] + as_[2] + as_[3];
    s2 = aq_[0] + aq_[1] + aq_[2] + aq_[3];
    const float mean = sv / NSTATF;
    const float var = s2 / NSTATF - mean*mean;
    const float istd = rsqrtf(var + 1e-5f);
    const float a = g[c] * istd;
    A[c] = a;
    Bc[c] = be[c] - mean * a;
  }
}

// ---------------- k5: out = relu(bn2(y2) + bnp(yp)), NHWC -> NCHW fp32 ----------------
__global__ __launch_bounds__(256) void k5(const u16* __restrict__ y2, const u16* __restrict__ yp,
    const float* __restrict__ A2, const float* __restrict__ B2c,
    const float* __restrict__ Ap, const float* __restrict__ Bp,
    float* __restrict__ outp)
{
  __shared__ float T[CC*K5S];
  __shared__ float cA2[64], cB2[64], cAp[64], cBp[64];
  const int tid = threadIdx.x;
  const int lane = tid & 63, wv = tid >> 6;
  const int wt = blockIdx.x, h = blockIdx.y, n = blockIdx.z;
  const int w0 = wt*256;
  if (tid < 64) { cA2[tid] = A2[tid]; cB2[tid] = B2c[tid]; cAp[tid] = Ap[tid]; cBp[tid] = Bp[tid]; }
  __syncthreads();
  const u16* p2 = y2 + ((size_t)(n*HH + h)*WW + w0)*CC;
  const u16* pp = yp + ((size_t)(n*HH + h)*WW + w0)*CC;
#pragma unroll
  for (int it = 0; it < 8; ++it) {
    const int j = it*256 + tid;
    const int w = j >> 3, c8 = j & 7;
    const uint4 u2 = *(const uint4*)(p2 + (size_t)w*CC + c8*8);
    const uint4 up = *(const uint4*)(pp + (size_t)w*CC + c8*8);
    const u32* m2 = (const u32*)&u2;
    const u32* mp = (const u32*)&up;
    const u32 sw = ((u32)(c8 & 3)) << 3;   // (c>>3)&3 == c8&3 for c = c8*8+...
#pragma unroll
    for (int h2 = 0; h2 < 4; ++h2) {
      const int c = c8*8 + h2*2;
      const float a = bf2f((u16)(m2[h2] & 0xFFFFu)), b = bf2f((u16)(m2[h2] >> 16));
      const float ra = bf2f((u16)(mp[h2] & 0xFFFFu)), rb = bf2f((u16)(mp[h2] >> 16));
      const u32 wsw = (u32)w ^ sw;
      T[(u32)(c    )*K5S + wsw] = fmaxf(a*cA2[c]   + cB2[c]   + ra*cAp[c]   + cBp[c],   0.f);
      T[(u32)(c + 1)*K5S + wsw] = fmaxf(b*cA2[c+1] + cB2[c+1] + rb*cAp[c+1] + cBp[c+1], 0.f);
    }
  }
  __syncthreads();
  // write phase: one channel per wave-instruction -> 1KB contiguous stores
#pragma unroll
  for (int cc = 0; cc < 16; ++cc) {
    const int c = cc*4 + wv;
    const u32 sw = ((u32)((c >> 3) & 3)) << 3;
    const u32 idx = (u32)c*K5S + (((u32)lane*4) ^ sw);
    const f32x4 v = *(const f32x4*)(T + idx);
    *(f32x4*)(outp + ((size_t)((n*CC + c)*HH + h))*WW + w0 + lane*4) = v;
  }
}

extern "C" void kernel_launch(void* const* d_in, const int* in_sizes, int n_in,
                              void* d_out, int out_size, void* d_ws, size_t ws_size,
                              hipStream_t stream)
{
  (void)in_sizes; (void)n_in; (void)out_size;
  const float* x   = (const float*)d_in[0];
  const float* w1  = (const float*)d_in[1];
  const float* b1  = (const float*)d_in[2];
  const float* g1  = (const float*)d_in[3];
  const float* be1 = (const float*)d_in[4];
  const float* w2  = (const float*)d_in[5];
  const float* b2  = (const float*)d_in[6];
  const float* g2  = (const float*)d_in[7];
  const float* be2 = (const float*)d_in[8];
  const float* wp  = (const float*)d_in[9];
  const float* bp  = (const float*)d_in[10];
  const float* gp  = (const float*)d_in[11];
  const float* bep = (const float*)d_in[12];

  const size_t TENB = (size_t)2*CC*PLANE*2;   // one bf16 tensor: 67,108,864 B
  char* ws = (char*)d_ws;
  u16* bufA = (u16*)ws;                    // xh, later y2
  u16* bufB = (u16*)(ws + TENB);           // y1
  u16* bufC = (u16*)(ws + TENB*2);         // yp
  char* aux = ws + TENB*3;
  u16* wb1 = (u16*)aux;                              // 73728 B
  u16* wb2 = (u16*)(aux + 73728);                    // 73728 B
  u16* wbp = (u16*)(aux + 147456);                   // 8192 B
  float* ps1 = (float*)(aux + 155648);               // 64*1024*4
  float* pq1 = ps1 + 64*NBC;
  float* ps2 = pq1 + 64*NBC;
  float* pq2 = ps2 + 64*NBC;
  float* psp = pq2 + 64*NBC;                         // 64*4096*4
  float* pqp = psp + 64*NBP;
  float* A1  = pqp + 64*NBP;
  float* B1  = A1 + 64;
  float* A2  = B1 + 64;
  float* B2c = A2 + 64;
  float* Ap  = B2c + 64;
  float* Bp  = Ap + 64;
  const size_t need = (size_t)(Bp + 64 - (float*)ws) * 4;
  if (ws_size < need) return;

  kprep<<<19, 512, 0, stream>>>(w1, w2, wp, wb1, wb2, wbp);
  k0<<<dim3(2, HH, 2), 256, 0, stream>>>(x, wbp, bp, bufA, bufC, psp, pqp);
  kconv<false><<<dim3(16, 16, 2), 256, 0, stream>>>(bufA, wb1, b1, nullptr, nullptr,
                                                    bufB, ps1, pq1);
  kfin2<<<128, 256, 0, stream>>>(ps1, pq1, g1, be1, A1, B1, NBC,
                                 psp, pqp, gp, bep, Ap, Bp, NBP);
  kconv<true><<<dim3(16, 16, 2), 256, 0, stream>>>(bufB, wb2, b2, A1, B1,
                                                   bufA, ps2, pq2);
  kfin2<<<64, 256, 0, stream>>>(ps2, pq2, g2, be2, A2, B2c, NBC,
                                ps2, pq2, g2, be2, A2, B2c, NBC);
  k5<<<dim3(2, HH, 2), 256, 0, stream>>>(bufA, bufC, A2, B2c, Ap, Bp, (float*)d_out);
}